// Round 2
// baseline (361.972 us; speedup 1.0000x reference)
//

#include <hip/hip_runtime.h>

// R21 = R19 structure (verified 275us/dispatch, absmax 0.0039) with RPB 4->8,
// grid 512->256 (1 block/CU). R20 post-mortem: xg-hoist cut MFMA work 37.5%
// (MfmaUtil 21.7->12.9 as predicted) but wall ROSE 275->300 -> step loop is
// NOT MFMA-bound; hoist reverted. New theory: the 2 co-resident blocks/CU
// duplicate the z-GEMM (each uses only 4 of 16 MFMA M-rows) and double
// barrier/LDS traffic. M=16 tiles fit 8 batch rows in the SAME 16 MFMAs:
// per-CU per-step MFMA + phase-A VALU + barriers all halve; gate math total
// unchanged (200 threads x 2 row-quads). Math per row is bit-identical to
// R19. LDS 77KB; launch_bounds(256,1) since only 1 block/CU exists anyway.

typedef unsigned short u16;
typedef unsigned int   u32;
typedef float f32x4 __attribute__((ext_vector_type(4)));
typedef short s16x8 __attribute__((ext_vector_type(8)));

__device__ __forceinline__ float bf2f(u16 u){
  union { u32 i; float f; } v; v.i = ((u32)u) << 16; return v.f;
}
__device__ __forceinline__ u16 f2bf(float f){
  union { float fl; u32 i; } v; v.fl = f;
  u32 r = v.i + 0x7fffu + ((v.i >> 16) & 1u);   // RNE
  return (u16)(r >> 16);
}
__device__ __forceinline__ float frcp(float x){ return __builtin_amdgcn_rcpf(x); }
__device__ __forceinline__ float sigm_f(float x){          // fast sigmoid
  float e = __expf(-x);
  return frcp(1.f + e);
}
__device__ __forceinline__ float tanh_f(float x){          // fast tanh, clamped
  x = fminf(fmaxf(x, -15.f), 15.f);
  float e = __expf(-2.f * x);
  return (1.f - e) * frcp(1.f + e);
}
__device__ __forceinline__ f32x4 mf(s16x8 a, s16x8 b, f32x4 c){
  return __builtin_amdgcn_mfma_f32_16x16x32_bf16(a, b, c, 0, 0, 0);
}
__device__ __forceinline__ float ldf(const void* p, int i, bool f32in){
  if (f32in) return ((const float*)p)[i];
  return bf2f(((const u16*)p)[i]);
}

#define TPB 256
#define RPB 8      // batch rows per block -> 256 blocks, 1 block/CU

extern "C" __global__ __launch_bounds__(TPB, 1) void LSTM_Seq2Dis_15272903704706_kernel(
    const int* idx, const void* emb, const void* Wk, const void* Uk,
    const void* bias, const void* W1, const void* b1,
    const void* W2, const void* b2, float* out)
{
  __shared__ __align__(16) u16 ering[16][1024];   // e per chunk step (frag layout, 32 KB)
  __shared__ __align__(16) u16 abuf[2][1024];     // h frags, double buffer (rows 0..7 live)
  __shared__ __align__(16) u16 hbuf[8][2][512];   // chunk h for dense head (128 M-rows, 16 KB)
  __shared__ __align__(16) u16 dwork[4][2][512];  // per-wave d1 scratch
  __shared__ float zl[8*212];                     // z[8][200] stride 212
  __shared__ float cl[8*52];                      // cell state
  __shared__ float bl[208];                       // LSTM bias
  __shared__ int   tokl[2048];                    // token ids [s][r], r 0..7
  __shared__ int   s_f32;

  const int tid = threadIdx.x;
  const int wv  = tid >> 6, ln = tid & 63;
  const int r0  = blockIdx.x * RPB;

  if (tid == 0){
    const u32* ew = (const u32*)emb;
    int hits = 0;
    for (int i = 0; i < 64; i++){
      u32 ef = (ew[i] >> 7) & 0xFFu;
      if (ef >= 112u && ef <= 127u) hits++;
    }
    s_f32 = (hits < 32) ? 1 : 0;
  }

  for (int i = tid; i < 16*1024; i += TPB) ((u16*)ering)[i] = 0;
  for (int i = tid; i < 2*1024;  i += TPB) ((u16*)abuf)[i]  = 0;
  for (int i = tid; i < 8*2*512; i += TPB) ((u16*)hbuf)[i]  = 0;
  for (int i = tid; i < 8*52;    i += TPB) cl[i] = 0.f;
  for (int i = tid; i < 2048;    i += TPB){
    int r = i & 7, s = i >> 3;
    tokl[i] = idx[(r0 + r)*256 + s];
  }
  __syncthreads();
  const bool f32in = (s_f32 != 0);
  for (int i = tid; i < 208; i += TPB) bl[i] = (i < 200) ? ldf(bias, i, f32in) : 0.f;

  // ---- z-GEMM B-fragments: k0..49 = Uk (h), k64..113 = Wk (e); N 200->256 ----
  // STATIC indexing only (R16 spill fix): wave owns nt = wv + 4t, t = 0..3.
  s16x8 bz[4][4];
  #pragma unroll
  for (int t = 0; t < 4; t++){
    int n = (wv + 4*t)*16 + (ln & 15);
    #pragma unroll
    for (int kt = 0; kt < 4; kt++){
      s16x8 v;
      #pragma unroll
      for (int j = 0; j < 8; j++){
        int k = kt*32 + ((ln >> 4) << 3) + j;
        float w = 0.f;
        if (n < 200){
          if (k < 50)                  w = ldf(Uk, k*200 + n, f32in);
          else if (k >= 64 && k < 114) w = ldf(Wk, (k-64)*200 + n, f32in);
        }
        v[j] = (short)f2bf(w);
      }
      bz[t][kt] = v;
    }
  }

  // ---- dense W1 fragments + b1/W2 (static loops) ----
  s16x8 w1f[4][2];
  float b1v[4], w2v[4];
  #pragma unroll
  for (int nt = 0; nt < 4; nt++){
    int c = nt*16 + (ln & 15);
    b1v[nt] = (c < 50) ? ldf(b1, c, f32in) : 0.f;
    w2v[nt] = (c < 50) ? ldf(W2, c, f32in) : 0.f;
    #pragma unroll
    for (int kt = 0; kt < 2; kt++){
      s16x8 v;
      #pragma unroll
      for (int j = 0; j < 8; j++){
        int k = kt*32 + ((ln >> 4) << 3) + j;
        v[j] = (short)((k < 50 && c < 50) ? f2bf(ldf(W1, k*50 + c, f32in)) : (u16)0);
      }
      w1f[nt][kt] = v;
    }
  }
  const float b2s = ldf(b2, 0, f32in);

  const int gr = tid / 50, gj = tid - gr*50;      // threads 0..199 own (gr,gj)
  const int foff = (gj >> 5)*512 + (gr + (((gj & 31) >> 3) << 4))*8 + (gj & 7);
  __syncthreads();

  for (int ch = 0; ch < 16; ch++){
    const int tc = ch*16;

    // ---- chunk gather: 16 steps of e, rows gr and gr+4, two vmcnt drains ----
    if (tid < 200){
      float ev[16];
      #pragma unroll
      for (int sl = 0; sl < 16; sl++)
        ev[sl] = ldf(emb, tokl[(tc + sl)*8 + gr]*50 + gj, f32in);
      #pragma unroll
      for (int sl = 0; sl < 16; sl++)
        ering[sl][foff] = f2bf(ev[sl]);
      #pragma unroll
      for (int sl = 0; sl < 16; sl++)
        ev[sl] = ldf(emb, tokl[(tc + sl)*8 + gr + 4]*50 + gj, f32in);
      #pragma unroll
      for (int sl = 0; sl < 16; sl++)
        ering[sl][foff + 32] = f2bf(ev[sl]);     // row m = gr+4 -> +4*8 bytes
    }
    __syncthreads();

    for (int sl = 0; sl < 16; sl++){
      const int s   = tc + sl;
      const int cur = s & 1, nxt = cur ^ 1;

      // ---- phase A: z = [h|e](8x128) @ [Uk;Wk](128x256) via MFMA ----
      s16x8 av[4];
      av[0] = *(const s16x8*)&abuf[cur][ln*8];
      av[1] = *(const s16x8*)&abuf[cur][512 + ln*8];
      av[2] = *(const s16x8*)&ering[sl][ln*8];
      av[3] = *(const s16x8*)&ering[sl][512 + ln*8];
      #pragma unroll
      for (int t = 0; t < 4; t++){
        f32x4 acc = {0.f,0.f,0.f,0.f};
        #pragma unroll
        for (int kt = 0; kt < 4; kt++) acc = mf(av[kt], bz[t][kt], acc);
        const int q = ln >> 4;
        if (q < 2){                                // rows 0..7 valid
          int col = (wv + 4*t)*16 + (ln & 15);
          if (col < 200){
            #pragma unroll
            for (int r = 0; r < 4; r++) zl[(q*4 + r)*212 + col] = acc[r];
          }
        }
      }
      __syncthreads();

      // ---- phase B: gates -> c,h for rows gr and gr+4 ----
      if (tid < 200){
        #pragma unroll
        for (int p = 0; p < 2; p++){
          const int rr = gr + 4*p;
          float zi = zl[rr*212 + gj]       + bl[gj];
          float zf = zl[rr*212 + 50 + gj]  + bl[50 + gj];
          float zg = zl[rr*212 + 100 + gj] + bl[100 + gj];
          float zo = zl[rr*212 + 150 + gj] + bl[150 + gj];
          float iv = sigm_f(zi), fv = sigm_f(zf), gv = tanh_f(zg), ov = sigm_f(zo);
          float c  = fv * cl[rr*52 + gj] + iv * gv;
          cl[rr*52 + gj] = c;
          u16 hb = f2bf(ov * tanh_f(c));
          abuf[nxt][foff + 32*p] = hb;
          int m = sl*8 + rr;
          hbuf[m >> 4][gj >> 5][((m & 15) + (((gj & 31) >> 3) << 4))*8 + (gj & 7)] = hb;
        }
      }

      // ---- dense head once per chunk (2 M-tiles per wave) ----
      if (sl == 15){
        __syncthreads();
        #pragma unroll
        for (int p = 0; p < 2; p++){
          const int mt = 2*wv + p;
          s16x8 a0 = *(const s16x8*)&hbuf[mt][0][ln*8];
          s16x8 a1 = *(const s16x8*)&hbuf[mt][1][ln*8];
          #pragma unroll
          for (int nt = 0; nt < 4; nt++){           // d1 = relu(h@W1+b1)
            f32x4 acc = {0.f,0.f,0.f,0.f};
            acc = mf(a0, w1f[nt][0], acc);
            acc = mf(a1, w1f[nt][1], acc);
            int c = nt*16 + (ln & 15);
            #pragma unroll
            for (int r = 0; r < 4; r++){
              float v = fmaxf(acc[r] + b1v[nt], 0.f);
              int row16 = ((ln >> 4) << 2) + r;
              dwork[wv][c >> 5][(row16 + (((c & 31) >> 3) << 4))*8 + (c & 7)] = f2bf(v);
            }
          }
          s16x8 d0 = *(const s16x8*)&dwork[wv][0][ln*8];
          s16x8 d1 = *(const s16x8*)&dwork[wv][1][ln*8];
          float part[4] = {0.f,0.f,0.f,0.f};
          #pragma unroll
          for (int nt = 0; nt < 4; nt++){           // d2 = relu(d1@W1+b1) . W2
            f32x4 acc = {0.f,0.f,0.f,0.f};
            acc = mf(d0, w1f[nt][0], acc);
            acc = mf(d1, w1f[nt][1], acc);
            #pragma unroll
            for (int r = 0; r < 4; r++)
              part[r] += fmaxf(acc[r] + b1v[nt], 0.f) * w2v[nt];
          }
          #pragma unroll
          for (int d = 1; d < 16; d <<= 1)
            #pragma unroll
            for (int r = 0; r < 4; r++) part[r] += __shfl_xor(part[r], d, 16);
          if ((ln & 15) == 0){
            int q = ln >> 4;
            #pragma unroll
            for (int r = 0; r < 4; r++){
              int m = mt*16 + (q << 2) + r;
              int sl8 = m >> 3, rb = m & 7;
              float z = part[r] + b2s;
              z = fmaxf(fminf(z, 1.0f), -1.0f);     // safety clamp
              out[(r0 + rb)*256 + tc + sl8] = sigm_f(z);
            }
          }
        }
      }
      __syncthreads();
    }
  }
}

extern "C" void kernel_launch(void* const* d_in, const int* in_sizes, int n_in,
                              void* d_out, int out_size, void* d_ws, size_t ws_size,
                              hipStream_t stream) {
  (void)in_sizes; (void)n_in; (void)out_size; (void)d_ws; (void)ws_size;
  hipLaunchKernelGGL(LSTM_Seq2Dis_15272903704706_kernel,
                     dim3(256), dim3(TPB), 0, stream,
                     (const int*)d_in[0], d_in[1], d_in[2], d_in[3], d_in[4],
                     d_in[5], d_in[6], d_in[7], d_in[8], (float*)d_out);
}

// Round 3
// 318.085 us; speedup vs baseline: 1.1380x; 1.1380x over previous
//

#include <hip/hip_runtime.h>

// R22 = R21 layout (RPB=8, verified absmax 0.0039) with the zl round-trip
// ELIMINATED via gate-major B-column permutation. Evidence: R20 (-37% MFMA
// work) and R21 (-50% per-CU everything) both left the ~2800cy/step wall
// unchanged -> step is bound by the serial latency chain (2 LDS round-trips
// + 2 barrier drains per step), not throughput. Fix: wave wv owns hidden
// units j in [wv*16,wv*16+16); its 4 MFMA N-tiles are the 4 GATES of those
// j's (B col = t*50+j). After 4 MFMA chains a lane holds i,f,g,o for
// (row,j) in registers: gates in-register, c-state in registers (cl gone),
// bias in registers (bl gone), zl gone, ONE barrier/step instead of two.
// Every output column's dot product is unchanged -> bit-identical math.

typedef unsigned short u16;
typedef unsigned int   u32;
typedef float f32x4 __attribute__((ext_vector_type(4)));
typedef short s16x8 __attribute__((ext_vector_type(8)));

__device__ __forceinline__ float bf2f(u16 u){
  union { u32 i; float f; } v; v.i = ((u32)u) << 16; return v.f;
}
__device__ __forceinline__ u16 f2bf(float f){
  union { float fl; u32 i; } v; v.fl = f;
  u32 r = v.i + 0x7fffu + ((v.i >> 16) & 1u);   // RNE
  return (u16)(r >> 16);
}
__device__ __forceinline__ float frcp(float x){ return __builtin_amdgcn_rcpf(x); }
__device__ __forceinline__ float sigm_f(float x){          // fast sigmoid
  float e = __expf(-x);
  return frcp(1.f + e);
}
__device__ __forceinline__ float tanh_f(float x){          // fast tanh, clamped
  x = fminf(fmaxf(x, -15.f), 15.f);
  float e = __expf(-2.f * x);
  return (1.f - e) * frcp(1.f + e);
}
__device__ __forceinline__ f32x4 mf(s16x8 a, s16x8 b, f32x4 c){
  return __builtin_amdgcn_mfma_f32_16x16x32_bf16(a, b, c, 0, 0, 0);
}
__device__ __forceinline__ float ldf(const void* p, int i, bool f32in){
  if (f32in) return ((const float*)p)[i];
  return bf2f(((const u16*)p)[i]);
}

#define TPB 256
#define RPB 8      // batch rows per block -> 256 blocks, 1 block/CU

extern "C" __global__ __launch_bounds__(TPB, 1) void LSTM_Seq2Dis_15272903704706_kernel(
    const int* idx, const void* emb, const void* Wk, const void* Uk,
    const void* bias, const void* W1, const void* b1,
    const void* W2, const void* b2, float* out)
{
  __shared__ __align__(16) u16 ering[16][1024];   // e per chunk step (frag layout, 32 KB)
  __shared__ __align__(16) u16 abuf[2][1024];     // h frags, double buffer (rows 0..7 live)
  __shared__ __align__(16) u16 hbuf[8][2][512];   // chunk h for dense head (128 M-rows, 16 KB)
  __shared__ __align__(16) u16 dwork[4][2][512];  // per-wave d1 scratch
  __shared__ int   tokl[2048];                    // token ids [s][r], r 0..7
  __shared__ int   s_f32;

  const int tid = threadIdx.x;
  const int wv  = tid >> 6, ln = tid & 63;
  const int r0  = blockIdx.x * RPB;

  if (tid == 0){
    const u32* ew = (const u32*)emb;
    int hits = 0;
    for (int i = 0; i < 64; i++){
      u32 ef = (ew[i] >> 7) & 0xFFu;
      if (ef >= 112u && ef <= 127u) hits++;
    }
    s_f32 = (hits < 32) ? 1 : 0;
  }

  for (int i = tid; i < 16*1024; i += TPB) ((u16*)ering)[i] = 0;
  for (int i = tid; i < 2*1024;  i += TPB) ((u16*)abuf)[i]  = 0;
  for (int i = tid; i < 8*2*512; i += TPB) ((u16*)hbuf)[i]  = 0;
  for (int i = tid; i < 2048;    i += TPB){
    int r = i & 7, s = i >> 3;
    tokl[i] = idx[(r0 + r)*256 + s];
  }
  __syncthreads();
  const bool f32in = (s_f32 != 0);

  // ---- z-GEMM B-frags, GATE-MAJOR cols: this wave-lane owns hidden unit
  // jown = wv*16 + (ln&15); tile t = gate t, B col = t*50 + jown.
  // k0..49 = Uk rows (h), k64..113 = Wk rows (e). STATIC indexing only.
  const int jown = wv*16 + (ln & 15);
  const bool jval = (jown < 50);
  s16x8 bz[4][4];
  #pragma unroll
  for (int t = 0; t < 4; t++){
    const int col = t*50 + jown;
    #pragma unroll
    for (int kt = 0; kt < 4; kt++){
      s16x8 v;
      #pragma unroll
      for (int j = 0; j < 8; j++){
        int k = kt*32 + ((ln >> 4) << 3) + j;
        float w = 0.f;
        if (jval){
          if (k < 50)                  w = ldf(Uk, k*200 + col, f32in);
          else if (k >= 64 && k < 114) w = ldf(Wk, (k-64)*200 + col, f32in);
        }
        v[j] = (short)f2bf(w);
      }
      bz[t][kt] = v;
    }
  }
  float bg[4];
  #pragma unroll
  for (int t = 0; t < 4; t++)
    bg[t] = jval ? ldf(bias, t*50 + jown, f32in) : 0.f;

  // ---- dense W1 fragments + b1/W2 (static loops) ----
  s16x8 w1f[4][2];
  float b1v[4], w2v[4];
  #pragma unroll
  for (int nt = 0; nt < 4; nt++){
    int c = nt*16 + (ln & 15);
    b1v[nt] = (c < 50) ? ldf(b1, c, f32in) : 0.f;
    w2v[nt] = (c < 50) ? ldf(W2, c, f32in) : 0.f;
    #pragma unroll
    for (int kt = 0; kt < 2; kt++){
      s16x8 v;
      #pragma unroll
      for (int j = 0; j < 8; j++){
        int k = kt*32 + ((ln >> 4) << 3) + j;
        v[j] = (short)((k < 50 && c < 50) ? f2bf(ldf(W1, k*50 + c, f32in)) : (u16)0);
      }
      w1f[nt][kt] = v;
    }
  }
  const float b2s = ldf(b2, 0, f32in);

  const int gr = tid / 50, gj = tid - gr*50;      // threads 0..199 own (gr,gj)
  const int foff = (gj >> 5)*512 + (gr + (((gj & 31) >> 3) << 4))*8 + (gj & 7);

  // per-lane persistent cell state: rows q*4+r (q=ln>>4, valid q<2), unit jown
  const int q = ln >> 4;
  float creg[4] = {0.f, 0.f, 0.f, 0.f};
  // h / hbuf write offsets for (row = q*4 + r, j = jown), r stride = 8 u16
  const int aoff = (jown >> 5)*512 + ((q*4) + (((jown & 31) >> 3) << 4))*8 + (jown & 7);
  __syncthreads();

  for (int ch = 0; ch < 16; ch++){
    const int tc = ch*16;

    // ---- chunk gather: 16 steps of e, rows gr and gr+4 ----
    if (tid < 200){
      float ev[16];
      #pragma unroll
      for (int sl = 0; sl < 16; sl++)
        ev[sl] = ldf(emb, tokl[(tc + sl)*8 + gr]*50 + gj, f32in);
      #pragma unroll
      for (int sl = 0; sl < 16; sl++)
        ering[sl][foff] = f2bf(ev[sl]);
      #pragma unroll
      for (int sl = 0; sl < 16; sl++)
        ev[sl] = ldf(emb, tokl[(tc + sl)*8 + gr + 4]*50 + gj, f32in);
      #pragma unroll
      for (int sl = 0; sl < 16; sl++)
        ering[sl][foff + 32] = f2bf(ev[sl]);     // row m = gr+4 -> +4*8 u16
    }
    __syncthreads();

    for (int sl = 0; sl < 16; sl++){
      const int s   = tc + sl;
      const int cur = s & 1, nxt = cur ^ 1;

      // ---- z = [h|e](8x128) @ [Uk;Wk]perm(128x256): 4 gate tiles/wave ----
      s16x8 av[4];
      av[0] = *(const s16x8*)&abuf[cur][ln*8];
      av[1] = *(const s16x8*)&abuf[cur][512 + ln*8];
      av[2] = *(const s16x8*)&ering[sl][ln*8];
      av[3] = *(const s16x8*)&ering[sl][512 + ln*8];
      f32x4 g4[4];
      #pragma unroll
      for (int t = 0; t < 4; t++){
        f32x4 acc = {0.f,0.f,0.f,0.f};
        #pragma unroll
        for (int kt = 0; kt < 4; kt++) acc = mf(av[kt], bz[t][kt], acc);
        g4[t] = acc;
      }

      // ---- gates fully in-register (lane owns i,f,g,o of (row, jown)) ----
      u16 hb[4];
      #pragma unroll
      for (int r = 0; r < 4; r++){
        float iv = sigm_f(g4[0][r] + bg[0]);
        float fv = sigm_f(g4[1][r] + bg[1]);
        float gv = tanh_f(g4[2][r] + bg[2]);
        float ov = sigm_f(g4[3][r] + bg[3]);
        float c  = fv * creg[r] + iv * gv;
        creg[r] = c;
        hb[r] = f2bf(ov * tanh_f(c));
      }
      if (q < 2 && jval){
        #pragma unroll
        for (int r = 0; r < 4; r++){
          abuf[nxt][aoff + r*8] = hb[r];
          int m = sl*8 + q*4 + r;
          hbuf[m >> 4][jown >> 5][((m & 15) + (((jown & 31) >> 3) << 4))*8 + (jown & 7)] = hb[r];
        }
      }

      // ---- dense head once per chunk (2 M-tiles per wave) ----
      if (sl == 15){
        __syncthreads();
        #pragma unroll
        for (int p = 0; p < 2; p++){
          const int mt = 2*wv + p;
          s16x8 a0 = *(const s16x8*)&hbuf[mt][0][ln*8];
          s16x8 a1 = *(const s16x8*)&hbuf[mt][1][ln*8];
          #pragma unroll
          for (int nt = 0; nt < 4; nt++){           // d1 = relu(h@W1+b1)
            f32x4 acc = {0.f,0.f,0.f,0.f};
            acc = mf(a0, w1f[nt][0], acc);
            acc = mf(a1, w1f[nt][1], acc);
            int c = nt*16 + (ln & 15);
            #pragma unroll
            for (int r = 0; r < 4; r++){
              float v = fmaxf(acc[r] + b1v[nt], 0.f);
              int row16 = ((ln >> 4) << 2) + r;
              dwork[wv][c >> 5][(row16 + (((c & 31) >> 3) << 4))*8 + (c & 7)] = f2bf(v);
            }
          }
          s16x8 d0 = *(const s16x8*)&dwork[wv][0][ln*8];
          s16x8 d1 = *(const s16x8*)&dwork[wv][1][ln*8];
          float part[4] = {0.f,0.f,0.f,0.f};
          #pragma unroll
          for (int nt = 0; nt < 4; nt++){           // d2 = relu(d1@W1+b1) . W2
            f32x4 acc = {0.f,0.f,0.f,0.f};
            acc = mf(d0, w1f[nt][0], acc);
            acc = mf(d1, w1f[nt][1], acc);
            #pragma unroll
            for (int r = 0; r < 4; r++)
              part[r] += fmaxf(acc[r] + b1v[nt], 0.f) * w2v[nt];
          }
          #pragma unroll
          for (int d = 1; d < 16; d <<= 1)
            #pragma unroll
            for (int r = 0; r < 4; r++) part[r] += __shfl_xor(part[r], d, 16);
          if ((ln & 15) == 0){
            int qq = ln >> 4;
            #pragma unroll
            for (int r = 0; r < 4; r++){
              int m = mt*16 + (qq << 2) + r;
              int sl8 = m >> 3, rb = m & 7;
              float z = part[r] + b2s;
              z = fmaxf(fminf(z, 1.0f), -1.0f);     // safety clamp
              out[(r0 + rb)*256 + tc + sl8] = sigm_f(z);
            }
          }
        }
      }
      __syncthreads();   // h[nxt] complete -> next step may read
    }
  }
}

extern "C" void kernel_launch(void* const* d_in, const int* in_sizes, int n_in,
                              void* d_out, int out_size, void* d_ws, size_t ws_size,
                              hipStream_t stream) {
  (void)in_sizes; (void)n_in; (void)out_size; (void)d_ws; (void)ws_size;
  hipLaunchKernelGGL(LSTM_Seq2Dis_15272903704706_kernel,
                     dim3(256), dim3(TPB), 0, stream,
                     (const int*)d_in[0], d_in[1], d_in[2], d_in[3], d_in[4],
                     d_in[5], d_in[6], d_in[7], d_in[8], (float*)d_out);
}

// Round 4
// 299.935 us; speedup vs baseline: 1.2068x; 1.0605x over previous
//

#include <hip/hip_runtime.h>

// R23 = R22 (verified 261us, absmax 0.0039) + gate load-balancing via
// shfl_xor(32) + ering prefetch. R22 post-mortem: VALUBusy rose to 46%;
// gate block runs UNGUARDED on all 256 lanes with only q<2 lanes holding
// valid rows, each doing 4 rows (~20 v_exp + 20 v_rcp per wave per step
// ~= 1000cy of the 2460cy step). Fix: one shfl_xor(acc[r],32) per tile
// moves rows 2,3 to q+2 lanes -> EVERY lane computes exactly 2 rows
// (perfect spread, per-wave gate cost halves). Cell state migrates with
// the rows (creg[2]); per-(row,j) math bit-identical. Also: ering[sl+1]
// A-frags prefetched BEFORE the step barrier (they only depend on the
// chunk-start barrier), hiding ~60-100cy of LDS latency per step.

typedef unsigned short u16;
typedef unsigned int   u32;
typedef float f32x4 __attribute__((ext_vector_type(4)));
typedef short s16x8 __attribute__((ext_vector_type(8)));

__device__ __forceinline__ float bf2f(u16 u){
  union { u32 i; float f; } v; v.i = ((u32)u) << 16; return v.f;
}
__device__ __forceinline__ u16 f2bf(float f){
  union { float fl; u32 i; } v; v.fl = f;
  u32 r = v.i + 0x7fffu + ((v.i >> 16) & 1u);   // RNE
  return (u16)(r >> 16);
}
__device__ __forceinline__ float frcp(float x){ return __builtin_amdgcn_rcpf(x); }
__device__ __forceinline__ float sigm_f(float x){          // fast sigmoid
  float e = __expf(-x);
  return frcp(1.f + e);
}
__device__ __forceinline__ float tanh_f(float x){          // fast tanh, clamped
  x = fminf(fmaxf(x, -15.f), 15.f);
  float e = __expf(-2.f * x);
  return (1.f - e) * frcp(1.f + e);
}
__device__ __forceinline__ f32x4 mf(s16x8 a, s16x8 b, f32x4 c){
  return __builtin_amdgcn_mfma_f32_16x16x32_bf16(a, b, c, 0, 0, 0);
}
__device__ __forceinline__ float ldf(const void* p, int i, bool f32in){
  if (f32in) return ((const float*)p)[i];
  return bf2f(((const u16*)p)[i]);
}

#define TPB 256
#define RPB 8      // batch rows per block -> 256 blocks, 1 block/CU

extern "C" __global__ __launch_bounds__(TPB, 1) void LSTM_Seq2Dis_15272903704706_kernel(
    const int* idx, const void* emb, const void* Wk, const void* Uk,
    const void* bias, const void* W1, const void* b1,
    const void* W2, const void* b2, float* out)
{
  __shared__ __align__(16) u16 ering[16][1024];   // e per chunk step (frag layout, 32 KB)
  __shared__ __align__(16) u16 abuf[2][1024];     // h frags, double buffer (rows 0..7 live)
  __shared__ __align__(16) u16 hbuf[8][2][512];   // chunk h for dense head (128 M-rows, 16 KB)
  __shared__ __align__(16) u16 dwork[4][2][512];  // per-wave d1 scratch
  __shared__ int   tokl[2048];                    // token ids [s][r], r 0..7
  __shared__ int   s_f32;

  const int tid = threadIdx.x;
  const int wv  = tid >> 6, ln = tid & 63;
  const int r0  = blockIdx.x * RPB;

  if (tid == 0){
    const u32* ew = (const u32*)emb;
    int hits = 0;
    for (int i = 0; i < 64; i++){
      u32 ef = (ew[i] >> 7) & 0xFFu;
      if (ef >= 112u && ef <= 127u) hits++;
    }
    s_f32 = (hits < 32) ? 1 : 0;
  }

  for (int i = tid; i < 16*1024; i += TPB) ((u16*)ering)[i] = 0;
  for (int i = tid; i < 2*1024;  i += TPB) ((u16*)abuf)[i]  = 0;
  for (int i = tid; i < 8*2*512; i += TPB) ((u16*)hbuf)[i]  = 0;
  for (int i = tid; i < 2048;    i += TPB){
    int r = i & 7, s = i >> 3;
    tokl[i] = idx[(r0 + r)*256 + s];
  }
  __syncthreads();
  const bool f32in = (s_f32 != 0);

  // ---- z-GEMM B-frags, GATE-MAJOR cols: this wave-lane owns hidden unit
  // jown = wv*16 + (ln&15); tile t = gate t, B col = t*50 + jown.
  // k0..49 = Uk rows (h), k64..113 = Wk rows (e). STATIC indexing only.
  const int jown = wv*16 + (ln & 15);
  const bool jval = (jown < 50);
  s16x8 bz[4][4];
  #pragma unroll
  for (int t = 0; t < 4; t++){
    const int col = t*50 + jown;
    #pragma unroll
    for (int kt = 0; kt < 4; kt++){
      s16x8 v;
      #pragma unroll
      for (int j = 0; j < 8; j++){
        int k = kt*32 + ((ln >> 4) << 3) + j;
        float w = 0.f;
        if (jval){
          if (k < 50)                  w = ldf(Uk, k*200 + col, f32in);
          else if (k >= 64 && k < 114) w = ldf(Wk, (k-64)*200 + col, f32in);
        }
        v[j] = (short)f2bf(w);
      }
      bz[t][kt] = v;
    }
  }
  float bg[4];
  #pragma unroll
  for (int t = 0; t < 4; t++)
    bg[t] = jval ? ldf(bias, t*50 + jown, f32in) : 0.f;

  // ---- dense W1 fragments + b1/W2 (static loops) ----
  s16x8 w1f[4][2];
  float b1v[4], w2v[4];
  #pragma unroll
  for (int nt = 0; nt < 4; nt++){
    int c = nt*16 + (ln & 15);
    b1v[nt] = (c < 50) ? ldf(b1, c, f32in) : 0.f;
    w2v[nt] = (c < 50) ? ldf(W2, c, f32in) : 0.f;
    #pragma unroll
    for (int kt = 0; kt < 2; kt++){
      s16x8 v;
      #pragma unroll
      for (int j = 0; j < 8; j++){
        int k = kt*32 + ((ln >> 4) << 3) + j;
        v[j] = (short)((k < 50 && c < 50) ? f2bf(ldf(W1, k*50 + c, f32in)) : (u16)0);
      }
      w1f[nt][kt] = v;
    }
  }
  const float b2s = ldf(b2, 0, f32in);

  const int gr = tid / 50, gj = tid - gr*50;      // threads 0..199 own (gr,gj)
  const int foff = (gj >> 5)*512 + (gr + (((gj & 31) >> 3) << 4))*8 + (gj & 7);

  // ---- gate split: lane (q = ln>>4) computes rows rowbase+{0,1}, unit jown
  //   q=0 -> rows 0,1   q=1 -> rows 4,5   (own acc[0],acc[1])
  //   q=2 -> rows 2,3   q=3 -> rows 6,7   (acc[2],acc[3] via shfl_xor 32)
  const int q  = ln >> 4;
  const int hi = q >> 1;
  const int rowbase = (q & 1)*4 + hi*2;
  float creg[2] = {0.f, 0.f};                     // cell state, rows rowbase+rp
  const int eo16 = ((jown & 31) >> 3) << 4;
  const int aoff0 = (jown >> 5)*512 + (rowbase + eo16)*8 + (jown & 7);
  __syncthreads();

  for (int ch = 0; ch < 16; ch++){
    const int tc = ch*16;

    // ---- chunk gather: 16 steps of e, rows gr and gr+4 ----
    if (tid < 200){
      float ev[16];
      #pragma unroll
      for (int sl = 0; sl < 16; sl++)
        ev[sl] = ldf(emb, tokl[(tc + sl)*8 + gr]*50 + gj, f32in);
      #pragma unroll
      for (int sl = 0; sl < 16; sl++)
        ering[sl][foff] = f2bf(ev[sl]);
      #pragma unroll
      for (int sl = 0; sl < 16; sl++)
        ev[sl] = ldf(emb, tokl[(tc + sl)*8 + gr + 4]*50 + gj, f32in);
      #pragma unroll
      for (int sl = 0; sl < 16; sl++)
        ering[sl][foff + 32] = f2bf(ev[sl]);     // row m = gr+4 -> +4*8 u16
    }
    __syncthreads();

    // e A-frags for sl=0 (ering is chunk-constant after the barrier above)
    s16x8 e0 = *(const s16x8*)&ering[0][ln*8];
    s16x8 e1 = *(const s16x8*)&ering[0][512 + ln*8];

    for (int sl = 0; sl < 16; sl++){
      const int s   = tc + sl;
      const int cur = s & 1, nxt = cur ^ 1;

      // ---- z = [h|e](8x128) @ [Uk;Wk]perm(128x256): 4 gate tiles/wave ----
      s16x8 av0 = *(const s16x8*)&abuf[cur][ln*8];
      s16x8 av1 = *(const s16x8*)&abuf[cur][512 + ln*8];
      f32x4 g4[4];
      #pragma unroll
      for (int t = 0; t < 4; t++){
        f32x4 acc = {0.f,0.f,0.f,0.f};
        acc = mf(av0, bz[t][0], acc);
        acc = mf(av1, bz[t][1], acc);
        acc = mf(e0,  bz[t][2], acc);
        acc = mf(e1,  bz[t][3], acc);
        g4[t] = acc;
      }

      // ---- redistribute rows 2,3 to q+2 lanes; 2 rows per lane ----
      float zz[4][2];
      #pragma unroll
      for (int t = 0; t < 4; t++){
        float s2 = __shfl_xor(g4[t][2], 32);
        float s3 = __shfl_xor(g4[t][3], 32);
        zz[t][0] = hi ? s2 : g4[t][0];
        zz[t][1] = hi ? s3 : g4[t][1];
      }

      // ---- gates in-register, 2 rows per lane ----
      u16 hb[2];
      #pragma unroll
      for (int rp = 0; rp < 2; rp++){
        float iv = sigm_f(zz[0][rp] + bg[0]);
        float fv = sigm_f(zz[1][rp] + bg[1]);
        float gv = tanh_f(zz[2][rp] + bg[2]);
        float ov = sigm_f(zz[3][rp] + bg[3]);
        float c  = fv * creg[rp] + iv * gv;
        creg[rp] = c;
        hb[rp] = f2bf(ov * tanh_f(c));
      }
      if (jval){
        #pragma unroll
        for (int rp = 0; rp < 2; rp++){
          abuf[nxt][aoff0 + rp*8] = hb[rp];
          int m = sl*8 + rowbase + rp;
          hbuf[m >> 4][jown >> 5][((m & 15) + eo16)*8 + (jown & 7)] = hb[rp];
        }
      }

      // ---- dense head once per chunk (2 M-tiles per wave) ----
      if (sl == 15){
        __syncthreads();
        #pragma unroll
        for (int p = 0; p < 2; p++){
          const int mt = 2*wv + p;
          s16x8 a0 = *(const s16x8*)&hbuf[mt][0][ln*8];
          s16x8 a1 = *(const s16x8*)&hbuf[mt][1][ln*8];
          #pragma unroll
          for (int nt = 0; nt < 4; nt++){           // d1 = relu(h@W1+b1)
            f32x4 acc = {0.f,0.f,0.f,0.f};
            acc = mf(a0, w1f[nt][0], acc);
            acc = mf(a1, w1f[nt][1], acc);
            int c = nt*16 + (ln & 15);
            #pragma unroll
            for (int r = 0; r < 4; r++){
              float v = fmaxf(acc[r] + b1v[nt], 0.f);
              int row16 = ((ln >> 4) << 2) + r;
              dwork[wv][c >> 5][(row16 + (((c & 31) >> 3) << 4))*8 + (c & 7)] = f2bf(v);
            }
          }
          s16x8 d0 = *(const s16x8*)&dwork[wv][0][ln*8];
          s16x8 d1 = *(const s16x8*)&dwork[wv][1][ln*8];
          float part[4] = {0.f,0.f,0.f,0.f};
          #pragma unroll
          for (int nt = 0; nt < 4; nt++){           // d2 = relu(d1@W1+b1) . W2
            f32x4 acc = {0.f,0.f,0.f,0.f};
            acc = mf(d0, w1f[nt][0], acc);
            acc = mf(d1, w1f[nt][1], acc);
            #pragma unroll
            for (int r = 0; r < 4; r++)
              part[r] += fmaxf(acc[r] + b1v[nt], 0.f) * w2v[nt];
          }
          #pragma unroll
          for (int d = 1; d < 16; d <<= 1)
            #pragma unroll
            for (int r = 0; r < 4; r++) part[r] += __shfl_xor(part[r], d, 16);
          if ((ln & 15) == 0){
            int qq = ln >> 4;
            #pragma unroll
            for (int r = 0; r < 4; r++){
              int m = mt*16 + (qq << 2) + r;
              int sl8 = m >> 3, rb = m & 7;
              float z = part[r] + b2s;
              z = fmaxf(fminf(z, 1.0f), -1.0f);     // safety clamp
              out[(r0 + rb)*256 + tc + sl8] = sigm_f(z);
            }
          }
        }
      } else {
        // prefetch next step's e A-frags (chunk-constant region, no race)
        e0 = *(const s16x8*)&ering[sl + 1][ln*8];
        e1 = *(const s16x8*)&ering[sl + 1][512 + ln*8];
      }
      __syncthreads();   // h[nxt] complete -> next step may read
    }
  }
}

extern "C" void kernel_launch(void* const* d_in, const int* in_sizes, int n_in,
                              void* d_out, int out_size, void* d_ws, size_t ws_size,
                              hipStream_t stream) {
  (void)in_sizes; (void)n_in; (void)out_size; (void)d_ws; (void)ws_size;
  hipLaunchKernelGGL(LSTM_Seq2Dis_15272903704706_kernel,
                     dim3(256), dim3(TPB), 0, stream,
                     (const int*)d_in[0], d_in[1], d_in[2], d_in[3], d_in[4],
                     d_in[5], d_in[6], d_in[7], d_in[8], (float*)d_out);
}